// Round 14
// baseline (4751.426 us; speedup 1.0000x reference)
//
#include <hip/hip_runtime.h>
#include <hip/hip_bf16.h>
#include <stdint.h>

typedef unsigned short u16;
typedef __attribute__((ext_vector_type(8))) short short8;
typedef __attribute__((ext_vector_type(4))) float f32x4;

__device__ __forceinline__ float bf2f(u16 u) {
  union { uint32_t i; float f; } v; v.i = ((uint32_t)u) << 16; return v.f;
}
__device__ __forceinline__ u16 f2bf(float x) {
  union { float f; uint32_t i; } v; v.f = x;
  uint32_t r = v.i + 0x7FFFu + ((v.i >> 16) & 1u);
  return (u16)(r >> 16);
}
__device__ __forceinline__ void gld16(const void* g, void* l) {
  __builtin_amdgcn_global_load_lds((const __attribute__((address_space(1))) void*)g,
                                   (__attribute__((address_space(3))) void*)l, 16, 0, 0);
}

// ---------------- prep kernels ----------------

__global__ __launch_bounds__(256) void cvt_bf16_k(const float* __restrict__ in, u16* __restrict__ out, int n) {
  int i = (blockIdx.x * 256 + threadIdx.x) * 4;
  int stride = gridDim.x * 256 * 4;
  for (; i < n; i += stride) {
    float4 v = *(const float4*)(in + i);
    ushort4 o;
    o.x = f2bf(v.x); o.y = f2bf(v.y); o.z = f2bf(v.z); o.w = f2bf(v.w);
    *(ushort4*)(out + i) = o;
  }
}

// W [Kd][Nd] f32 -> Wt [Nd][Kd] bf16  (64x64 tiles via LDS)
__global__ __launch_bounds__(256) void transpose_cvt_k(const float* __restrict__ W, u16* __restrict__ Wt,
                                                        int Kd, int Nd) {
  __shared__ float lds[64][68];
  int t = threadIdx.x;
  int n0 = blockIdx.x * 64, k0 = blockIdx.y * 64;
  int kr = t >> 2, cq = (t & 3) * 16;
  const float* src = W + (size_t)(k0 + kr) * Nd + n0 + cq;
  float4 a = *(const float4*)(src);
  float4 b = *(const float4*)(src + 4);
  float4 c = *(const float4*)(src + 8);
  float4 d = *(const float4*)(src + 12);
  *(float4*)&lds[kr][cq]      = a;
  *(float4*)&lds[kr][cq + 4]  = b;
  *(float4*)&lds[kr][cq + 8]  = c;
  *(float4*)&lds[kr][cq + 12] = d;
  __syncthreads();
  int rn = t >> 2, ks = (t & 3) * 16;
  u16 tmp[16];
  #pragma unroll
  for (int j = 0; j < 16; ++j) tmp[j] = f2bf(lds[ks + j][rn]);
  u16* dst = Wt + (size_t)(n0 + rn) * Kd + k0 + ks;
  *(short8*)dst       = *(short8*)tmp;
  *(short8*)(dst + 8) = *(short8*)(tmp + 8);
}

// cos/sin table: tab[m*128 + i] = cos, tab[m*128 + 64 + i] = sin, i in [0,64)
__global__ __launch_bounds__(64) void rope_table_k(const int* __restrict__ pos, float* __restrict__ tab) {
  int m = blockIdx.x, i = threadIdx.x;
  float p = (float)pos[m];
  float inv = expf(-(float)i * (9.210340371976184f / 64.0f)); // ln(10000)/64
  float ang = p * inv;
  float sn, cs;
  sincosf(ang, &sn, &cs);
  tab[m * 128 + i] = cs;
  tab[m * 128 + 64 + i] = sn;
}

// ---------------- 256x256 GEMM, r5 schedule with BK=32 (2 blocks/CU) ----------------
// EXACT r5 4-phase ring scaled to BK=32: per tile {P1 read a_lo/b_lo + stage Ah1(t+1);
// P2 read b_hi + stage Bh0(t+1); P3 read a_hi + stage Bh1(t+1); P4 stage Ah0(t+2)};
// one counted wait per tile at end-P4 (vmcnt(1) = r5's vmcnt(2) at 1 load/stage).
// LDS 64KB -> 2 blocks/CU: second block's MFMA overlaps this block's barrier drain (m114).

__device__ __forceinline__ void stage_half(const u16* __restrict__ G, u16* S, int K,
                                           int tile, int half, int w, int sr, int scsw) {
  int d = tile & 1;
  int sm = half * 8 + w;
  const u16* g = G + (size_t)(sm * 16 + sr) * K + (tile << 5) + scsw;
  u16* s = S + (size_t)(d * 16 + sm) * 512;
  gld16(g, s);
}

__device__ __forceinline__ short8 frag(const u16* S, int d, int sidx, int fo) {
  return *(const short8*)&S[(size_t)((d * 16 + sidx) * 512) + fo];
}

template <int F32OUT>
__global__ __launch_bounds__(512, 4) void gemm256_k(const u16* __restrict__ A, const u16* __restrict__ Bt,
                                                    void* __restrict__ Cp, int N, int K, int GX) {
  __shared__ u16 As[2 * 16 * 512];
  __shared__ u16 Bs[2 * 16 * 512];
  // 2D XCD-region mapping: grid GY x GX split into 2x4 regions of SY x SX blocks.
  int lid = blockIdx.x;
  int GY = gridDim.x / GX;
  int SY = GY >> 1, SX = GX >> 2;
  int xcd = lid & 7, idx = lid >> 3;
  int ry = xcd >> 2, rx = xcd & 3;
  int bxl = idx / SY, byl = idx - bxl * SY;
  int by = ry * SY + byl, bx = rx * SX + bxl;
  int bm0 = by << 8, bn0 = bx << 8;
  int tid = threadIdx.x, w = tid >> 6, l = tid & 63;
  int wr = w >> 2, wc = w & 3;
  const u16* Ag = A + (size_t)bm0 * K;
  const u16* Bg = Bt + (size_t)bn0 * K;
  int NT = K >> 5;
  int sr = l >> 2;
  int scsw = ((l & 3) * 8) ^ ((sr & 8) ? 16 : 0);
  int fr = l & 15;
  int g = l >> 4;
  int fo = fr * 32 + ((g * 8) ^ ((fr & 8) ? 16 : 0));

  f32x4 acc[8][4];
  #pragma unroll
  for (int i = 0; i < 8; ++i)
    #pragma unroll
    for (int j = 0; j < 4; ++j) acc[i][j] = (f32x4){0.f, 0.f, 0.f, 0.f};

  // prologue: tile0 fully, tile1 Ah0 (mirrors r5; vmcnt(1) leaves Ah0(1) pending)
  stage_half(Ag, As, K, 0, 0, w, sr, scsw);
  stage_half(Ag, As, K, 0, 1, w, sr, scsw);
  stage_half(Bg, Bs, K, 0, 0, w, sr, scsw);
  stage_half(Bg, Bs, K, 0, 1, w, sr, scsw);
  stage_half(Ag, As, K, 1, 0, w, sr, scsw);
  asm volatile("s_waitcnt vmcnt(1)" ::: "memory");
  __builtin_amdgcn_s_barrier();
  __builtin_amdgcn_sched_barrier(0);

  for (int t = 0; t < NT; ++t) {
    int d = t & 1;
    short8 a_lo[4], a_hi[4], b_lo[2], b_hi[2];
    // ---- P1: read a_lo,b_lo; stage Ah1(t+1); barrier; MFMA q1
    #pragma unroll
    for (int fm = 0; fm < 4; ++fm) a_lo[fm] = frag(As, d, wr * 8 + fm, fo);
    #pragma unroll
    for (int fn = 0; fn < 2; ++fn) b_lo[fn] = frag(Bs, d, wc * 4 + fn, fo);
    if (t + 1 < NT) stage_half(Ag, As, K, t + 1, 1, w, sr, scsw);
    __builtin_amdgcn_s_barrier();
    __builtin_amdgcn_s_setprio(1);
    #pragma unroll
    for (int fm = 0; fm < 4; ++fm)
      #pragma unroll
      for (int fn = 0; fn < 2; ++fn)
        acc[fm][fn] = __builtin_amdgcn_mfma_f32_16x16x32_bf16(a_lo[fm], b_lo[fn], acc[fm][fn], 0, 0, 0);
    __builtin_amdgcn_s_setprio(0);
    __builtin_amdgcn_s_barrier();
    // ---- P2: read b_hi; stage Bh0(t+1); barrier; MFMA q2
    #pragma unroll
    for (int fn = 0; fn < 2; ++fn) b_hi[fn] = frag(Bs, d, wc * 4 + 2 + fn, fo);
    if (t + 1 < NT) stage_half(Bg, Bs, K, t + 1, 0, w, sr, scsw);
    __builtin_amdgcn_s_barrier();
    __builtin_amdgcn_s_setprio(1);
    #pragma unroll
    for (int fm = 0; fm < 4; ++fm)
      #pragma unroll
      for (int fn = 0; fn < 2; ++fn)
        acc[fm][2 + fn] = __builtin_amdgcn_mfma_f32_16x16x32_bf16(a_lo[fm], b_hi[fn], acc[fm][2 + fn], 0, 0, 0);
    __builtin_amdgcn_s_setprio(0);
    __builtin_amdgcn_s_barrier();
    // ---- P3: read a_hi; stage Bh1(t+1); barrier; MFMA q3
    #pragma unroll
    for (int fm = 0; fm < 4; ++fm) a_hi[fm] = frag(As, d, wr * 8 + 4 + fm, fo);
    if (t + 1 < NT) stage_half(Bg, Bs, K, t + 1, 1, w, sr, scsw);
    __builtin_amdgcn_s_barrier();
    __builtin_amdgcn_s_setprio(1);
    #pragma unroll
    for (int fm = 0; fm < 4; ++fm)
      #pragma unroll
      for (int fn = 0; fn < 2; ++fn)
        acc[4 + fm][2 + fn] = __builtin_amdgcn_mfma_f32_16x16x32_bf16(a_hi[fm], b_hi[fn], acc[4 + fm][2 + fn], 0, 0, 0);
    __builtin_amdgcn_s_setprio(0);
    __builtin_amdgcn_s_barrier();
    // ---- P4: stage Ah0(t+2); MFMA q4; counted vmcnt; barrier
    if (t + 2 < NT) stage_half(Ag, As, K, t + 2, 0, w, sr, scsw);
    __builtin_amdgcn_s_setprio(1);
    #pragma unroll
    for (int fm = 0; fm < 4; ++fm)
      #pragma unroll
      for (int fn = 0; fn < 2; ++fn)
        acc[4 + fm][fn] = __builtin_amdgcn_mfma_f32_16x16x32_bf16(a_hi[fm], b_lo[fn], acc[4 + fm][fn], 0, 0, 0);
    __builtin_amdgcn_s_setprio(0);
    if (t + 2 < NT) asm volatile("s_waitcnt vmcnt(1)" ::: "memory");
    else            asm volatile("s_waitcnt vmcnt(0)" ::: "memory");
    __builtin_amdgcn_s_barrier();
    __builtin_amdgcn_sched_barrier(0);
  }

  int r0 = bm0 + wr * 128 + (g << 2);
  int c0 = bn0 + wc * 64 + fr;
  #pragma unroll
  for (int fm = 0; fm < 8; ++fm)
    #pragma unroll
    for (int fn = 0; fn < 4; ++fn)
      #pragma unroll
      for (int r = 0; r < 4; ++r) {
        size_t idx2 = (size_t)(r0 + fm * 16 + r) * N + (c0 + fn * 16);
        if (F32OUT) ((float*)Cp)[idx2] = acc[fm][fn][r];
        else        ((u16*)Cp)[idx2]   = f2bf(acc[fm][fn][r]);
      }
}

// ---------------- RoPE rearrange ----------------

__global__ __launch_bounds__(256) void rope_qk_k(const u16* __restrict__ qkv, const float* __restrict__ tab,
                                                  u16* __restrict__ Qb, u16* __restrict__ Kb) {
  int m = blockIdx.x, t = threadIdx.x;
  int b = m >> 11, s = m & 2047;
  const float* tabm = tab + m * 128;
  #pragma unroll
  for (int part = 0; part < 2; ++part) {
    const u16* src = qkv + (size_t)m * 12288 + part * 4096;
    u16* dst = part ? Kb : Qb;
    float qs = part ? 1.0f : 0.08838834764831845f;
    #pragma unroll
    for (int it = 0; it < 2; ++it) {
      int v = t + it * 256;
      int h = v >> 4;
      int d1 = (v & 15) * 4;
      const u16* sp = src + h * 128 + d1;
      ushort4 x1 = *(const ushort4*)(sp);
      ushort4 x2 = *(const ushort4*)(sp + 64);
      float4 cs = *(const float4*)(tabm + d1);
      float4 sn = *(const float4*)(tabm + 64 + d1);
      ushort4 o1, o2;
      o1.x = f2bf((bf2f(x1.x) * cs.x - bf2f(x2.x) * sn.x) * qs);
      o1.y = f2bf((bf2f(x1.y) * cs.y - bf2f(x2.y) * sn.y) * qs);
      o1.z = f2bf((bf2f(x1.z) * cs.z - bf2f(x2.z) * sn.z) * qs);
      o1.w = f2bf((bf2f(x1.w) * cs.w - bf2f(x2.w) * sn.w) * qs);
      o2.x = f2bf((bf2f(x2.x) * cs.x + bf2f(x1.x) * sn.x) * qs);
      o2.y = f2bf((bf2f(x2.y) * cs.y + bf2f(x1.y) * sn.y) * qs);
      o2.z = f2bf((bf2f(x2.z) * cs.z + bf2f(x1.z) * sn.z) * qs);
      o2.w = f2bf((bf2f(x2.w) * cs.w + bf2f(x1.w) * sn.w) * qs);
      u16* o = dst + ((size_t)(b * 32 + h) * 2048 + s) * 128 + d1;
      *(ushort4*)o        = o1;
      *(ushort4*)(o + 64) = o2;
    }
  }
}

// v part of qkv -> Vt [bh][d][s]
__global__ __launch_bounds__(256) void v_transpose_k(const u16* __restrict__ qkv, u16* __restrict__ Vt) {
  __shared__ u16 lds[64][136];
  int bid = blockIdx.x;
  int bh = bid >> 5, st = bid & 31;
  int b = bh >> 5, h = bh & 31;
  int s0 = st * 64;
  int t = threadIdx.x;
  int r = t >> 2, cq = (t & 3) * 32;
  const u16* src = qkv + (size_t)(b * 2048 + s0 + r) * 12288 + 8192 + h * 128 + cq;
  *(short8*)&lds[r][cq]      = *(const short8*)(src);
  *(short8*)&lds[r][cq + 8]  = *(const short8*)(src + 8);
  *(short8*)&lds[r][cq + 16] = *(const short8*)(src + 16);
  *(short8*)&lds[r][cq + 24] = *(const short8*)(src + 24);
  __syncthreads();
  int d = t >> 1, sseg = (t & 1) * 32;
  u16 tmp[32];
  #pragma unroll
  for (int j = 0; j < 32; ++j) tmp[j] = lds[sseg + j][d];
  u16* o = Vt + (size_t)bh * (128 * 2048) + (size_t)d * 2048 + s0 + sseg;
  *(short8*)(o)      = *(short8*)(tmp);
  *(short8*)(o + 8)  = *(short8*)(tmp + 8);
  *(short8*)(o + 16) = *(short8*)(tmp + 16);
  *(short8*)(o + 24) = *(short8*)(tmp + 24);
}

// ---------------- flash attention (causal), bf16 MFMA ----------------

__device__ __forceinline__ void stage_kv(const u16* __restrict__ Kg, const u16* __restrict__ Vg,
                                         u16* Ksb, u16* Vsb, int j0, int w, int l) {
  #pragma unroll
  for (int c = 0; c < 2; ++c) {
    int rk = c * 32 + w * 4 + (l >> 4);
    int kcol = ((l & 15) * 8) ^ ((rk & 7) << 3);
    gld16(Kg + (size_t)(j0 + rk) * 128 + kcol, Ksb + (c * 32 + w * 4) * 128);
    int rv = c * 64 + w * 8 + (l >> 3);
    int vcol = ((l & 7) * 8) ^ ((rv & 7) << 3);
    gld16(Vg + (size_t)rv * 2048 + j0 + vcol, Vsb + (c * 64 + w * 8) * 64);
  }
}

__global__ __launch_bounds__(512, 2) void attn_k(const u16* __restrict__ Qb, const u16* __restrict__ Kb,
                                                  const u16* __restrict__ Vt, u16* __restrict__ attnb) {
  __shared__ u16 Ks[2][64 * 128];
  __shared__ u16 Vs[2][128 * 64];
  __shared__ u16 Ps[8][32 * 64];
  int lid = blockIdx.x + gridDim.x * blockIdx.y;
  int xcd = lid & 7, idx = lid >> 3;
  int bh = xcd * 8 + (idx & 7);
  int qt = 7 - (idx >> 3);            // heavy-first within each XCD
  int b = bh >> 5, h = bh & 31;
  int q0 = qt * 256;
  int t = threadIdx.x, w = t >> 6, l = t & 63;
  int g = l >> 4, fr = l & 15;
  const u16* Qg = Qb + (size_t)bh * (2048 * 128);
  const u16* Kg = Kb + (size_t)bh * (2048 * 128);
  const u16* Vg = Vt + (size_t)bh * (128 * 2048);

  short8 aq[2][4];
  #pragma unroll
  for (int fm = 0; fm < 2; ++fm)
    #pragma unroll
    for (int kk = 0; kk < 4; ++kk)
      aq[fm][kk] = *(const short8*)&Qg[(size_t)(q0 + w * 32 + fm * 16 + fr) * 128 + kk * 32 + g * 8];

  stage_kv(Kg, Vg, Ks[0], Vs[0], 0, w, l);
  __syncthreads();

  f32x4 zero = {0.f, 0.f, 0.f, 0.f};
  f32x4 o[2][8];
  #pragma unroll
  for (int fm = 0; fm < 2; ++fm)
    #pragma unroll
    for (int fd = 0; fd < 8; ++fd) o[fm][fd] = zero;
  float m_run[2][4], l_run[2][4];
  #pragma unroll
  for (int fm = 0; fm < 2; ++fm)
    #pragma unroll
    for (int r = 0; r < 4; ++r) { m_run[fm][r] = -1e30f; l_run[fm][r] = 0.f; }

  int NJ = 4 * qt + 4;
  for (int j = 0; j < NJ; ++j) {
    int j0 = j * 64;
    int cur = j & 1;
    if (j + 1 < NJ) stage_kv(Kg, Vg, Ks[cur ^ 1], Vs[cur ^ 1], j0 + 64, w, l);
    if (j0 < q0 + w * 32 + 32) {
      f32x4 sc[2][4];
      #pragma unroll
      for (int fm = 0; fm < 2; ++fm)
        #pragma unroll
        for (int fn = 0; fn < 4; ++fn) sc[fm][fn] = zero;
      __builtin_amdgcn_s_setprio(1);
      #pragma unroll
      for (int kk = 0; kk < 4; ++kk) {
        #pragma unroll
        for (int fn = 0; fn < 4; ++fn) {
          short8 bk = *(const short8*)&Ks[cur][(fn * 16 + fr) * 128 + ((kk * 32 + g * 8) ^ ((fr & 7) << 3))];
          #pragma unroll
          for (int fm = 0; fm < 2; ++fm)
            sc[fm][fn] = __builtin_amdgcn_mfma_f32_16x16x32_bf16(aq[fm][kk], bk, sc[fm][fn], 0, 0, 0);
        }
      }
      __builtin_amdgcn_s_setprio(0);
      int qb_ = q0 + w * 32 + (g << 2);
      int kb_ = j0 + fr;
      #pragma unroll
      for (int fm = 0; fm < 2; ++fm)
        #pragma unroll
        for (int fn = 0; fn < 4; ++fn)
          #pragma unroll
          for (int r = 0; r < 4; ++r)
            if (kb_ + fn * 16 > qb_ + fm * 16 + r) sc[fm][fn][r] = -1e30f;
      float mx[2][4];
      #pragma unroll
      for (int fm = 0; fm < 2; ++fm)
        #pragma unroll
        for (int r = 0; r < 4; ++r) {
          float v = fmaxf(fmaxf(sc[fm][0][r], sc[fm][1][r]), fmaxf(sc[fm][2][r], sc[fm][3][r]));
          v = fmaxf(v, __shfl_xor(v, 1));
          v = fmaxf(v, __shfl_xor(v, 2));
          v = fmaxf(v, __shfl_xor(v, 4));
          v = fmaxf(v, __shfl_xor(v, 8));
          mx[fm][r] = v;
        }
      float scale[2][4];
      #pragma unroll
      for (int fm = 0; fm < 2; ++fm)
        #pragma unroll
        for (int r = 0; r < 4; ++r) {
          float mn = fmaxf(m_run[fm][r], mx[fm][r]);
          scale[fm][r] = __expf(m_run[fm][r] - mn);
          m_run[fm][r] = mn;
        }
      float rs[2][4];
      #pragma unroll
      for (int fm = 0; fm < 2; ++fm)
        #pragma unroll
        for (int r = 0; r < 4; ++r) {
          float acc = 0.f;
          #pragma unroll
          for (int fn = 0; fn < 4; ++fn) {
            float p = __expf(sc[fm][fn][r] - m_run[fm][r]);
            sc[fm][fn][r] = p;
            acc += p;
          }
          acc += __shfl_xor(acc, 1);
          acc += __shfl_xor(acc, 2);
          acc += __shfl_xor(acc, 4);
          acc += __shfl_xor(acc, 8);
          rs[fm][r] = acc;
        }
      #pragma unroll
      for (int fm = 0; fm < 2; ++fm)
        #pragma unroll
        for (int r = 0; r < 4; ++r) l_run[fm][r] = l_run[fm][r] * scale[fm][r] + rs[fm][r];
      #pragma unroll
      for (int fm = 0; fm < 2; ++fm)
        #pragma unroll
        for (int fd = 0; fd < 8; ++fd)
          #pragma unroll
          for (int r = 0; r < 4; ++r) o[fm][fd][r] *= scale[fm][r];
      #pragma unroll
      for (int fm = 0; fm < 2; ++fm)
        #pragma unroll
        for (int fn = 0; fn < 4; ++fn)
          #pragma unroll
          for (int r = 0; r < 4; ++r) {
            int prow = fm * 16 + (g << 2) + r;
            Ps[w][prow * 64 + ((fn * 16 + fr) ^ ((prow & 7) << 3))] = f2bf(sc[fm][fn][r]);
          }
      __builtin_amdgcn_s_setprio(1);
      #pragma unroll
      for (int kk = 0; kk < 2; ++kk) {
        short8 pa[2];
        #pragma unroll
        for (int fm = 0; fm < 2; ++fm)
          pa[fm] = *(const short8*)&Ps[w][(fm * 16 + fr) * 64 + ((kk * 32 + g * 8) ^ ((fr & 7) << 3))];
        #pragma unroll
        for (int fd = 0; fd < 8; ++fd) {
          short8 bv = *(const short8*)&Vs[cur][(fd * 16 + fr) * 64 + ((kk * 32 + g * 8) ^ ((fr & 7) << 3))];
          #pragma unroll
          for (int fm = 0; fm < 2; ++fm)
            o[fm][fd] = __builtin_amdgcn_mfma_f32_16x16x32_bf16(pa[fm], bv, o[fm][fd], 0, 0, 0);
        }
      }
      __builtin_amdgcn_s_setprio(0);
    }
    __syncthreads();
  }

  #pragma unroll
  for (int fm = 0; fm < 2; ++fm)
    #pragma unroll
    for (int r = 0; r < 4; ++r) {
      float inv = 1.0f / l_run[fm][r];
      int srow = q0 + w * 32 + fm * 16 + (g << 2) + r;
      u16* dst = attnb + (size_t)(b * 2048 + srow) * 4096 + h * 128 + fr;
      #pragma unroll
      for (int fd = 0; fd < 8; ++fd)
        dst[fd * 16] = f2bf(o[fm][fd][r] * inv);
    }
}

// ---------------- launch ----------------

extern "C" void kernel_launch(void* const* d_in, const int* in_sizes, int n_in,
                              void* d_out, int out_size, void* d_ws, size_t ws_size,
                              hipStream_t stream) {
  const int*   positions = (const int*)d_in[0];
  const float* hidden    = (const float*)d_in[1];
  const float* W_qkv     = (const float*)d_in[2];
  const float* W_o       = (const float*)d_in[3];
  float* out = (float*)d_out;
  char* ws = (char*)d_ws;

  u16* R0 = (u16*)ws;
  u16* R1 = (u16*)(ws + 100663296);
  u16* R2 = (u16*)(ws + 201326592);
  float* tab = (float*)(ws + 234881024);

  u16* hidden_bf = R2;
  u16* Wqkv_t = R0;
  u16* qkv = R1;
  u16* Qb = R2;
  u16* Kb = R0;
  u16* Vt = R0 + 16777216;
  u16* attnb = R0 + 33554432;
  u16* Wo_t = R1;

  cvt_bf16_k<<<4096, 256, 0, stream>>>(hidden, hidden_bf, 16777216);
  transpose_cvt_k<<<dim3(192, 64), 256, 0, stream>>>(W_qkv, Wqkv_t, 4096, 12288);
  rope_table_k<<<4096, 64, 0, stream>>>(positions, tab);

  gemm256_k<0><<<768, 512, 0, stream>>>(hidden_bf, Wqkv_t, qkv, 12288, 4096, 48);

  rope_qk_k<<<4096, 256, 0, stream>>>(qkv, tab, Qb, Kb);
  v_transpose_k<<<2048, 256, 0, stream>>>(qkv, Vt);
  transpose_cvt_k<<<dim3(64, 64), 256, 0, stream>>>(W_o, Wo_t, 4096, 4096);

  attn_k<<<dim3(8, 64), 512, 0, stream>>>(Qb, Kb, Vt, attnb);

  gemm256_k<1><<<256, 512, 0, stream>>>(attnb, Wo_t, out, 4096, 4096, 16);
}

// Round 15
// 760.693 us; speedup vs baseline: 6.2462x; 6.2462x over previous
//
#include <hip/hip_runtime.h>
#include <hip/hip_bf16.h>
#include <stdint.h>

typedef unsigned short u16;
typedef __attribute__((ext_vector_type(8))) short short8;
typedef __attribute__((ext_vector_type(4))) float f32x4;

__device__ __forceinline__ float bf2f(u16 u) {
  union { uint32_t i; float f; } v; v.i = ((uint32_t)u) << 16; return v.f;
}
__device__ __forceinline__ u16 f2bf(float x) {
  union { float f; uint32_t i; } v; v.f = x;
  uint32_t r = v.i + 0x7FFFu + ((v.i >> 16) & 1u);
  return (u16)(r >> 16);
}
__device__ __forceinline__ void gld16(const void* g, void* l) {
  __builtin_amdgcn_global_load_lds((const __attribute__((address_space(1))) void*)g,
                                   (__attribute__((address_space(3))) void*)l, 16, 0, 0);
}

// ---------------- prep kernels ----------------

__global__ __launch_bounds__(256) void cvt_bf16_k(const float* __restrict__ in, u16* __restrict__ out, int n) {
  int i = (blockIdx.x * 256 + threadIdx.x) * 4;
  int stride = gridDim.x * 256 * 4;
  for (; i < n; i += stride) {
    float4 v = *(const float4*)(in + i);
    ushort4 o;
    o.x = f2bf(v.x); o.y = f2bf(v.y); o.z = f2bf(v.z); o.w = f2bf(v.w);
    *(ushort4*)(out + i) = o;
  }
}

// W [Kd][Nd] f32 -> Wt [Nd][Kd] bf16  (64x64 tiles via LDS)
__global__ __launch_bounds__(256) void transpose_cvt_k(const float* __restrict__ W, u16* __restrict__ Wt,
                                                        int Kd, int Nd) {
  __shared__ float lds[64][68];
  int t = threadIdx.x;
  int n0 = blockIdx.x * 64, k0 = blockIdx.y * 64;
  int kr = t >> 2, cq = (t & 3) * 16;
  const float* src = W + (size_t)(k0 + kr) * Nd + n0 + cq;
  float4 a = *(const float4*)(src);
  float4 b = *(const float4*)(src + 4);
  float4 c = *(const float4*)(src + 8);
  float4 d = *(const float4*)(src + 12);
  *(float4*)&lds[kr][cq]      = a;
  *(float4*)&lds[kr][cq + 4]  = b;
  *(float4*)&lds[kr][cq + 8]  = c;
  *(float4*)&lds[kr][cq + 12] = d;
  __syncthreads();
  int rn = t >> 2, ks = (t & 3) * 16;
  u16 tmp[16];
  #pragma unroll
  for (int j = 0; j < 16; ++j) tmp[j] = f2bf(lds[ks + j][rn]);
  u16* dst = Wt + (size_t)(n0 + rn) * Kd + k0 + ks;
  *(short8*)dst       = *(short8*)tmp;
  *(short8*)(dst + 8) = *(short8*)(tmp + 8);
}

// cos/sin table: tab[m*128 + i] = cos, tab[m*128 + 64 + i] = sin, i in [0,64)
__global__ __launch_bounds__(64) void rope_table_k(const int* __restrict__ pos, float* __restrict__ tab) {
  int m = blockIdx.x, i = threadIdx.x;
  float p = (float)pos[m];
  float inv = expf(-(float)i * (9.210340371976184f / 64.0f)); // ln(10000)/64
  float ang = p * inv;
  float sn, cs;
  sincosf(ang, &sn, &cs);
  tab[m * 128 + i] = cs;
  tab[m * 128 + 64 + i] = sn;
}

// ---------------- 256x256 GEMM, r5 schedule (measured local optimum) ----------------
// Per tile: 4 phases {stage half; barrier; setprio; MFMA quadrant; barrier};
// staging ring A(t+1)h1@P1, B(t+1)h0@P2, B(t+1)h1@P3, A(t+2)h0@P4; vmcnt(2) at tile end.

__device__ __forceinline__ void stage_half(const u16* __restrict__ G, u16* S, int K,
                                           int tile, int half, int w, int sr, int scsw) {
  int d = tile & 1;
  int sm = half * 8 + w;
  const u16* g = G + (size_t)(sm * 16 + sr) * K + (tile << 6) + scsw;
  u16* s = S + (size_t)(d * 32 + sm * 2) * 512;
  gld16(g, s);
  gld16(g + 32, s + 512);
}

__device__ __forceinline__ short8 frag(const u16* S, int d, int sidx, int kk, int fo) {
  return *(const short8*)&S[(size_t)((d * 32 + sidx * 2 + kk) * 512) + fo];
}

template <int F32OUT>
__global__ __launch_bounds__(512) void gemm256_k(const u16* __restrict__ A, const u16* __restrict__ Bt,
                                                 void* __restrict__ Cp, int N, int K, int GX) {
  __shared__ u16 As[2 * 32 * 512];
  __shared__ u16 Bs[2 * 32 * 512];
  // 2D XCD-region mapping: grid GY x GX split into 2x4 regions of SY x SX blocks.
  int lid = blockIdx.x;
  int GY = gridDim.x / GX;
  int SY = GY >> 1, SX = GX >> 2;
  int xcd = lid & 7, idx = lid >> 3;
  int ry = xcd >> 2, rx = xcd & 3;
  int bxl = idx / SY, byl = idx - bxl * SY;
  int by = ry * SY + byl, bx = rx * SX + bxl;
  int bm0 = by << 8, bn0 = bx << 8;
  int tid = threadIdx.x, w = tid >> 6, l = tid & 63;
  int wr = w >> 2, wc = w & 3;
  const u16* Ag = A + (size_t)bm0 * K;
  const u16* Bg = Bt + (size_t)bn0 * K;
  int NT = K >> 6;
  int sr = l >> 2;
  int scsw = ((l & 3) * 8) ^ ((sr & 8) ? 16 : 0);
  int fr = l & 15;
  int fo = fr * 32 + (((l >> 4) * 8) ^ ((fr & 8) ? 16 : 0));

  f32x4 acc[8][4];
  #pragma unroll
  for (int i = 0; i < 8; ++i)
    #pragma unroll
    for (int j = 0; j < 4; ++j) acc[i][j] = (f32x4){0.f, 0.f, 0.f, 0.f};

  stage_half(Ag, As, K, 0, 0, w, sr, scsw);
  stage_half(Ag, As, K, 0, 1, w, sr, scsw);
  stage_half(Bg, Bs, K, 0, 0, w, sr, scsw);
  stage_half(Bg, Bs, K, 0, 1, w, sr, scsw);
  stage_half(Ag, As, K, 1, 0, w, sr, scsw);
  asm volatile("s_waitcnt vmcnt(2)" ::: "memory");
  __builtin_amdgcn_s_barrier();
  __builtin_amdgcn_sched_barrier(0);

  for (int t = 0; t < NT; ++t) {
    int d = t & 1;
    short8 a_lo[4][2], a_hi[4][2], b_lo[2][2], b_hi[2][2];
    // ---- P1: read a_lo,b_lo; stage A(t+1)h1; barrier; MFMA q1
    #pragma unroll
    for (int fm = 0; fm < 4; ++fm) {
      a_lo[fm][0] = frag(As, d, wr * 8 + fm, 0, fo);
      a_lo[fm][1] = frag(As, d, wr * 8 + fm, 1, fo);
    }
    #pragma unroll
    for (int fn = 0; fn < 2; ++fn) {
      b_lo[fn][0] = frag(Bs, d, wc * 4 + fn, 0, fo);
      b_lo[fn][1] = frag(Bs, d, wc * 4 + fn, 1, fo);
    }
    if (t + 1 < NT) stage_half(Ag, As, K, t + 1, 1, w, sr, scsw);
    __builtin_amdgcn_s_barrier();
    __builtin_amdgcn_s_setprio(1);
    #pragma unroll
    for (int fm = 0; fm < 4; ++fm)
      #pragma unroll
      for (int fn = 0; fn < 2; ++fn) {
        acc[fm][fn] = __builtin_amdgcn_mfma_f32_16x16x32_bf16(a_lo[fm][0], b_lo[fn][0], acc[fm][fn], 0, 0, 0);
        acc[fm][fn] = __builtin_amdgcn_mfma_f32_16x16x32_bf16(a_lo[fm][1], b_lo[fn][1], acc[fm][fn], 0, 0, 0);
      }
    __builtin_amdgcn_s_setprio(0);
    __builtin_amdgcn_s_barrier();
    // ---- P2: read b_hi; stage B(t+1)h0; barrier; MFMA q2
    #pragma unroll
    for (int fn = 0; fn < 2; ++fn) {
      b_hi[fn][0] = frag(Bs, d, wc * 4 + 2 + fn, 0, fo);
      b_hi[fn][1] = frag(Bs, d, wc * 4 + 2 + fn, 1, fo);
    }
    if (t + 1 < NT) stage_half(Bg, Bs, K, t + 1, 0, w, sr, scsw);
    __builtin_amdgcn_s_barrier();
    __builtin_amdgcn_s_setprio(1);
    #pragma unroll
    for (int fm = 0; fm < 4; ++fm)
      #pragma unroll
      for (int fn = 0; fn < 2; ++fn) {
        acc[fm][2 + fn] = __builtin_amdgcn_mfma_f32_16x16x32_bf16(a_lo[fm][0], b_hi[fn][0], acc[fm][2 + fn], 0, 0, 0);
        acc[fm][2 + fn] = __builtin_amdgcn_mfma_f32_16x16x32_bf16(a_lo[fm][1], b_hi[fn][1], acc[fm][2 + fn], 0, 0, 0);
      }
    __builtin_amdgcn_s_setprio(0);
    __builtin_amdgcn_s_barrier();
    // ---- P3: read a_hi; stage B(t+1)h1; barrier; MFMA q3
    #pragma unroll
    for (int fm = 0; fm < 4; ++fm) {
      a_hi[fm][0] = frag(As, d, wr * 8 + 4 + fm, 0, fo);
      a_hi[fm][1] = frag(As, d, wr * 8 + 4 + fm, 1, fo);
    }
    if (t + 1 < NT) stage_half(Bg, Bs, K, t + 1, 1, w, sr, scsw);
    __builtin_amdgcn_s_barrier();
    __builtin_amdgcn_s_setprio(1);
    #pragma unroll
    for (int fm = 0; fm < 4; ++fm)
      #pragma unroll
      for (int fn = 0; fn < 2; ++fn) {
        acc[4 + fm][2 + fn] = __builtin_amdgcn_mfma_f32_16x16x32_bf16(a_hi[fm][0], b_hi[fn][0], acc[4 + fm][2 + fn], 0, 0, 0);
        acc[4 + fm][2 + fn] = __builtin_amdgcn_mfma_f32_16x16x32_bf16(a_hi[fm][1], b_hi[fn][1], acc[4 + fm][2 + fn], 0, 0, 0);
      }
    __builtin_amdgcn_s_setprio(0);
    __builtin_amdgcn_s_barrier();
    // ---- P4: stage A(t+2)h0; MFMA q4; counted vmcnt; barrier
    if (t + 2 < NT) stage_half(Ag, As, K, t + 2, 0, w, sr, scsw);
    __builtin_amdgcn_s_setprio(1);
    #pragma unroll
    for (int fm = 0; fm < 4; ++fm)
      #pragma unroll
      for (int fn = 0; fn < 2; ++fn) {
        acc[4 + fm][fn] = __builtin_amdgcn_mfma_f32_16x16x32_bf16(a_hi[fm][0], b_lo[fn][0], acc[4 + fm][fn], 0, 0, 0);
        acc[4 + fm][fn] = __builtin_amdgcn_mfma_f32_16x16x32_bf16(a_hi[fm][1], b_lo[fn][1], acc[4 + fm][fn], 0, 0, 0);
      }
    __builtin_amdgcn_s_setprio(0);
    if (t + 2 < NT) asm volatile("s_waitcnt vmcnt(2)" ::: "memory");
    else            asm volatile("s_waitcnt vmcnt(0)" ::: "memory");
    __builtin_amdgcn_s_barrier();
    __builtin_amdgcn_sched_barrier(0);
  }

  int r0 = bm0 + wr * 128 + ((l >> 4) << 2);
  int c0 = bn0 + wc * 64 + (l & 15);
  #pragma unroll
  for (int fm = 0; fm < 8; ++fm)
    #pragma unroll
    for (int fn = 0; fn < 4; ++fn)
      #pragma unroll
      for (int r = 0; r < 4; ++r) {
        size_t idx2 = (size_t)(r0 + fm * 16 + r) * N + (c0 + fn * 16);
        if (F32OUT) ((float*)Cp)[idx2] = acc[fm][fn][r];
        else        ((u16*)Cp)[idx2]   = f2bf(acc[fm][fn][r]);
      }
}

// ---------------- RoPE rearrange ----------------

__global__ __launch_bounds__(256) void rope_qk_k(const u16* __restrict__ qkv, const float* __restrict__ tab,
                                                  u16* __restrict__ Qb, u16* __restrict__ Kb) {
  int m = blockIdx.x, t = threadIdx.x;
  int b = m >> 11, s = m & 2047;
  const float* tabm = tab + m * 128;
  #pragma unroll
  for (int part = 0; part < 2; ++part) {
    const u16* src = qkv + (size_t)m * 12288 + part * 4096;
    u16* dst = part ? Kb : Qb;
    float qs = part ? 1.0f : 0.08838834764831845f;
    #pragma unroll
    for (int it = 0; it < 2; ++it) {
      int v = t + it * 256;
      int h = v >> 4;
      int d1 = (v & 15) * 4;
      const u16* sp = src + h * 128 + d1;
      ushort4 x1 = *(const ushort4*)(sp);
      ushort4 x2 = *(const ushort4*)(sp + 64);
      float4 cs = *(const float4*)(tabm + d1);
      float4 sn = *(const float4*)(tabm + 64 + d1);
      ushort4 o1, o2;
      o1.x = f2bf((bf2f(x1.x) * cs.x - bf2f(x2.x) * sn.x) * qs);
      o1.y = f2bf((bf2f(x1.y) * cs.y - bf2f(x2.y) * sn.y) * qs);
      o1.z = f2bf((bf2f(x1.z) * cs.z - bf2f(x2.z) * sn.z) * qs);
      o1.w = f2bf((bf2f(x1.w) * cs.w - bf2f(x2.w) * sn.w) * qs);
      o2.x = f2bf((bf2f(x2.x) * cs.x + bf2f(x1.x) * sn.x) * qs);
      o2.y = f2bf((bf2f(x2.y) * cs.y + bf2f(x1.y) * sn.y) * qs);
      o2.z = f2bf((bf2f(x2.z) * cs.z + bf2f(x1.z) * sn.z) * qs);
      o2.w = f2bf((bf2f(x2.w) * cs.w + bf2f(x1.w) * sn.w) * qs);
      u16* o = dst + ((size_t)(b * 32 + h) * 2048 + s) * 128 + d1;
      *(ushort4*)o        = o1;
      *(ushort4*)(o + 64) = o2;
    }
  }
}

// v part of qkv -> Vt [bh][d][s]
__global__ __launch_bounds__(256) void v_transpose_k(const u16* __restrict__ qkv, u16* __restrict__ Vt) {
  __shared__ u16 lds[64][136];
  int bid = blockIdx.x;
  int bh = bid >> 5, st = bid & 31;
  int b = bh >> 5, h = bh & 31;
  int s0 = st * 64;
  int t = threadIdx.x;
  int r = t >> 2, cq = (t & 3) * 32;
  const u16* src = qkv + (size_t)(b * 2048 + s0 + r) * 12288 + 8192 + h * 128 + cq;
  *(short8*)&lds[r][cq]      = *(const short8*)(src);
  *(short8*)&lds[r][cq + 8]  = *(const short8*)(src + 8);
  *(short8*)&lds[r][cq + 16] = *(const short8*)(src + 16);
  *(short8*)&lds[r][cq + 24] = *(const short8*)(src + 24);
  __syncthreads();
  int d = t >> 1, sseg = (t & 1) * 32;
  u16 tmp[32];
  #pragma unroll
  for (int j = 0; j < 32; ++j) tmp[j] = lds[sseg + j][d];
  u16* o = Vt + (size_t)bh * (128 * 2048) + (size_t)d * 2048 + s0 + sseg;
  *(short8*)(o)      = *(short8*)(tmp);
  *(short8*)(o + 8)  = *(short8*)(tmp + 8);
  *(short8*)(o + 16) = *(short8*)(tmp + 16);
  *(short8*)(o + 24) = *(short8*)(tmp + 24);
}

// ---------------- flash attention (causal), bf16 MFMA ----------------

__device__ __forceinline__ void stage_kv(const u16* __restrict__ Kg, const u16* __restrict__ Vg,
                                         u16* Ksb, u16* Vsb, int j0, int w, int l) {
  #pragma unroll
  for (int c = 0; c < 2; ++c) {
    int rk = c * 32 + w * 4 + (l >> 4);
    int kcol = ((l & 15) * 8) ^ ((rk & 7) << 3);
    gld16(Kg + (size_t)(j0 + rk) * 128 + kcol, Ksb + (c * 32 + w * 4) * 128);
    int rv = c * 64 + w * 8 + (l >> 3);
    int vcol = ((l & 7) * 8) ^ ((rv & 7) << 3);
    gld16(Vg + (size_t)rv * 2048 + j0 + vcol, Vsb + (c * 64 + w * 8) * 64);
  }
}

__global__ __launch_bounds__(512, 2) void attn_k(const u16* __restrict__ Qb, const u16* __restrict__ Kb,
                                                  const u16* __restrict__ Vt, u16* __restrict__ attnb) {
  __shared__ u16 Ks[2][64 * 128];
  __shared__ u16 Vs[2][128 * 64];
  __shared__ u16 Ps[8][32 * 64];
  int lid = blockIdx.x + gridDim.x * blockIdx.y;
  int xcd = lid & 7, idx = lid >> 3;
  int bh = xcd * 8 + (idx & 7);
  int qt = 7 - (idx >> 3);            // heavy-first within each XCD
  int b = bh >> 5, h = bh & 31;
  int q0 = qt * 256;
  int t = threadIdx.x, w = t >> 6, l = t & 63;
  int g = l >> 4, fr = l & 15;
  const u16* Qg = Qb + (size_t)bh * (2048 * 128);
  const u16* Kg = Kb + (size_t)bh * (2048 * 128);
  const u16* Vg = Vt + (size_t)bh * (128 * 2048);

  short8 aq[2][4];
  #pragma unroll
  for (int fm = 0; fm < 2; ++fm)
    #pragma unroll
    for (int kk = 0; kk < 4; ++kk)
      aq[fm][kk] = *(const short8*)&Qg[(size_t)(q0 + w * 32 + fm * 16 + fr) * 128 + kk * 32 + g * 8];

  stage_kv(Kg, Vg, Ks[0], Vs[0], 0, w, l);
  __syncthreads();

  f32x4 zero = {0.f, 0.f, 0.f, 0.f};
  f32x4 o[2][8];
  #pragma unroll
  for (int fm = 0; fm < 2; ++fm)
    #pragma unroll
    for (int fd = 0; fd < 8; ++fd) o[fm][fd] = zero;
  float m_run[2][4], l_run[2][4];
  #pragma unroll
  for (int fm = 0; fm < 2; ++fm)
    #pragma unroll
    for (int r = 0; r < 4; ++r) { m_run[fm][r] = -1e30f; l_run[fm][r] = 0.f; }

  int NJ = 4 * qt + 4;
  for (int j = 0; j < NJ; ++j) {
    int j0 = j * 64;
    int cur = j & 1;
    if (j + 1 < NJ) stage_kv(Kg, Vg, Ks[cur ^ 1], Vs[cur ^ 1], j0 + 64, w, l);
    if (j0 < q0 + w * 32 + 32) {
      f32x4 sc[2][4];
      #pragma unroll
      for (int fm = 0; fm < 2; ++fm)
        #pragma unroll
        for (int fn = 0; fn < 4; ++fn) sc[fm][fn] = zero;
      __builtin_amdgcn_s_setprio(1);
      #pragma unroll
      for (int kk = 0; kk < 4; ++kk) {
        #pragma unroll
        for (int fn = 0; fn < 4; ++fn) {
          short8 bk = *(const short8*)&Ks[cur][(fn * 16 + fr) * 128 + ((kk * 32 + g * 8) ^ ((fr & 7) << 3))];
          #pragma unroll
          for (int fm = 0; fm < 2; ++fm)
            sc[fm][fn] = __builtin_amdgcn_mfma_f32_16x16x32_bf16(aq[fm][kk], bk, sc[fm][fn], 0, 0, 0);
        }
      }
      __builtin_amdgcn_s_setprio(0);
      int qb_ = q0 + w * 32 + (g << 2);
      int kb_ = j0 + fr;
      #pragma unroll
      for (int fm = 0; fm < 2; ++fm)
        #pragma unroll
        for (int fn = 0; fn < 4; ++fn)
          #pragma unroll
          for (int r = 0; r < 4; ++r)
            if (kb_ + fn * 16 > qb_ + fm * 16 + r) sc[fm][fn][r] = -1e30f;
      float mx[2][4];
      #pragma unroll
      for (int fm = 0; fm < 2; ++fm)
        #pragma unroll
        for (int r = 0; r < 4; ++r) {
          float v = fmaxf(fmaxf(sc[fm][0][r], sc[fm][1][r]), fmaxf(sc[fm][2][r], sc[fm][3][r]));
          v = fmaxf(v, __shfl_xor(v, 1));
          v = fmaxf(v, __shfl_xor(v, 2));
          v = fmaxf(v, __shfl_xor(v, 4));
          v = fmaxf(v, __shfl_xor(v, 8));
          mx[fm][r] = v;
        }
      float scale[2][4];
      #pragma unroll
      for (int fm = 0; fm < 2; ++fm)
        #pragma unroll
        for (int r = 0; r < 4; ++r) {
          float mn = fmaxf(m_run[fm][r], mx[fm][r]);
          scale[fm][r] = __expf(m_run[fm][r] - mn);
          m_run[fm][r] = mn;
        }
      float rs[2][4];
      #pragma unroll
      for (int fm = 0; fm < 2; ++fm)
        #pragma unroll
        for (int r = 0; r < 4; ++r) {
          float acc = 0.f;
          #pragma unroll
          for (int fn = 0; fn < 4; ++fn) {
            float p = __expf(sc[fm][fn][r] - m_run[fm][r]);
            sc[fm][fn][r] = p;
            acc += p;
          }
          acc += __shfl_xor(acc, 1);
          acc += __shfl_xor(acc, 2);
          acc += __shfl_xor(acc, 4);
          acc += __shfl_xor(acc, 8);
          rs[fm][r] = acc;
        }
      #pragma unroll
      for (int fm = 0; fm < 2; ++fm)
        #pragma unroll
        for (int r = 0; r < 4; ++r) l_run[fm][r] = l_run[fm][r] * scale[fm][r] + rs[fm][r];
      #pragma unroll
      for (int fm = 0; fm < 2; ++fm)
        #pragma unroll
        for (int fd = 0; fd < 8; ++fd)
          #pragma unroll
          for (int r = 0; r < 4; ++r) o[fm][fd][r] *= scale[fm][r];
      #pragma unroll
      for (int fm = 0; fm < 2; ++fm)
        #pragma unroll
        for (int fn = 0; fn < 4; ++fn)
          #pragma unroll
          for (int r = 0; r < 4; ++r) {
            int prow = fm * 16 + (g << 2) + r;
            Ps[w][prow * 64 + ((fn * 16 + fr) ^ ((prow & 7) << 3))] = f2bf(sc[fm][fn][r]);
          }
      __builtin_amdgcn_s_setprio(1);
      #pragma unroll
      for (int kk = 0; kk < 2; ++kk) {
        short8 pa[2];
        #pragma unroll
        for (int fm = 0; fm < 2; ++fm)
          pa[fm] = *(const short8*)&Ps[w][(fm * 16 + fr) * 64 + ((kk * 32 + g * 8) ^ ((fr & 7) << 3))];
        #pragma unroll
        for (int fd = 0; fd < 8; ++fd) {
          short8 bv = *(const short8*)&Vs[cur][(fd * 16 + fr) * 64 + ((kk * 32 + g * 8) ^ ((fr & 7) << 3))];
          #pragma unroll
          for (int fm = 0; fm < 2; ++fm)
            o[fm][fd] = __builtin_amdgcn_mfma_f32_16x16x32_bf16(pa[fm], bv, o[fm][fd], 0, 0, 0);
        }
      }
      __builtin_amdgcn_s_setprio(0);
    }
    __syncthreads();
  }

  #pragma unroll
  for (int fm = 0; fm < 2; ++fm)
    #pragma unroll
    for (int r = 0; r < 4; ++r) {
      float inv = 1.0f / l_run[fm][r];
      int srow = q0 + w * 32 + fm * 16 + (g << 2) + r;
      u16* dst = attnb + (size_t)(b * 2048 + srow) * 4096 + h * 128 + fr;
      #pragma unroll
      for (int fd = 0; fd < 8; ++fd)
        dst[fd * 16] = f2bf(o[fm][fd][r] * inv);
    }
}

// ---------------- launch ----------------

extern "C" void kernel_launch(void* const* d_in, const int* in_sizes, int n_in,
                              void* d_out, int out_size, void* d_ws, size_t ws_size,
                              hipStream_t stream) {
  const int*   positions = (const int*)d_in[0];
  const float* hidden    = (const float*)d_in[1];
  const float* W_qkv     = (const float*)d_in[2];
  const float* W_o       = (const float*)d_in[3];
  float* out = (float*)d_out;
  char* ws = (char*)d_ws;

  u16* R0 = (u16*)ws;
  u16* R1 = (u16*)(ws + 100663296);
  u16* R2 = (u16*)(ws + 201326592);
  float* tab = (float*)(ws + 234881024);

  u16* hidden_bf = R2;
  u16* Wqkv_t = R0;
  u16* qkv = R1;
  u16* Qb = R2;
  u16* Kb = R0;
  u16* Vt = R0 + 16777216;
  u16* attnb = R0 + 33554432;
  u16* Wo_t = R1;

  cvt_bf16_k<<<4096, 256, 0, stream>>>(hidden, hidden_bf, 16777216);
  transpose_cvt_k<<<dim3(192, 64), 256, 0, stream>>>(W_qkv, Wqkv_t, 4096, 12288);
  rope_table_k<<<4096, 64, 0, stream>>>(positions, tab);

  gemm256_k<0><<<768, 512, 0, stream>>>(hidden_bf, Wqkv_t, qkv, 12288, 4096, 48);

  rope_qk_k<<<4096, 256, 0, stream>>>(qkv, tab, Qb, Kb);
  v_transpose_k<<<2048, 256, 0, stream>>>(qkv, Vt);
  transpose_cvt_k<<<dim3(64, 64), 256, 0, stream>>>(W_o, Wo_t, 4096, 4096);

  attn_k<<<dim3(8, 64), 512, 0, stream>>>(Qb, Kb, Vt, attnb);

  gemm256_k<1><<<256, 512, 0, stream>>>(attnb, Wo_t, out, 4096, 4096, 16);
}